// Round 6
// baseline (424.752 us; speedup 1.0000x reference)
//
#include <hip/hip_runtime.h>
#include <hip/hip_bf16.h>

typedef __hip_bfloat16 bf16;

#define B_   4
#define C_   32
#define DW_  64
#define H_   256
#define W_   256
#define P_   65536
#define SRC_ 32
#define PPU_ 66564          // padded pair-plane, u32 elements (258*258)
#define PSTR_ 258

// ---- ws float-index offsets (small region) ----
#define OW1    0
#define OB1    2048
#define OW3    2112
#define OB3    3136
#define OWS    3168
#define OBS    4192
#define OW4    4224
#define OB4    6272
#define OW5    6336
#define OB5    7360
#define ON1W   7392
#define ON1B   7424
#define ON2W   7456
#define ON2B   7488
#define OBETA  7520
#define OGAMMA 7552
#define OSUMS  7584
#define OSVEC  7712
#define OFLAG  7900
// byte offsets
#define CWT_BOFF 40960ull                        // cwt fp32 transposed: 4*1024*576*4 = 9437184 B
#define T1_BOFF  (CWT_BOFF + 9437184ull)         // paired padded t1: 128*66564*4 = 34080768 B
#define G_BOFF   (T1_BOFF + 34080768ull)         // g bf16 pair-packed: 16777216 B

__device__ __forceinline__ float lo16f(unsigned u){ return __uint_as_float(u << 16); }
__device__ __forceinline__ float hi16f(unsigned u){ return __uint_as_float(u & 0xFFFF0000u); }
__device__ __forceinline__ float us2f(unsigned short u){ return __uint_as_float(((unsigned)u) << 16); }
__device__ __forceinline__ unsigned short bbits(float v){
    union { bf16 b; unsigned short u; } cv; cv.b = __float2bfloat16(v); return cv.u;
}
__device__ __forceinline__ unsigned pkf(float lo, float hi){
    return ((unsigned)bbits(hi) << 16) | bbits(lo);
}

template<typename T> __device__ __forceinline__ float ldf(const T* p);
template<> __device__ __forceinline__ float ldf<float>(const float* p){ return *p; }
template<> __device__ __forceinline__ float ldf<bf16>(const bf16* p){ return __bfloat162float(*p); }

// ---------------- k_setup: flag + weight prep + cw transpose + zpad ----------------
template<typename T>
__device__ void prep_body(const void* const* pp, float* wsf)
{
    int t = threadIdx.x;
    for (int i = t; i < 2048; i += 256) wsf[OW1 + i] = ldf<T>((const T*)pp[0] + i);
    for (int i = t; i < 64;   i += 256) wsf[OB1 + i] = ldf<T>((const T*)pp[1] + i);
    for (int i = t; i < 1024; i += 256) wsf[OW3 + i] = ldf<T>((const T*)pp[2] + i);
    for (int i = t; i < 32;   i += 256) wsf[OB3 + i] = ldf<T>((const T*)pp[3] + i);
    for (int i = t; i < 1024; i += 256) wsf[OWS + i] = ldf<T>((const T*)pp[4] + i);
    for (int i = t; i < 32;   i += 256) wsf[OBS + i] = ldf<T>((const T*)pp[5] + i);
    for (int i = t; i < 2048; i += 256) wsf[OW4 + i] = ldf<T>((const T*)pp[6] + i);
    for (int i = t; i < 64;   i += 256) wsf[OB4 + i] = ldf<T>((const T*)pp[7] + i);
    for (int i = t; i < 1024; i += 256) wsf[OW5 + i] = ldf<T>((const T*)pp[8] + i);
    for (int i = t; i < 32;   i += 256) wsf[OB5 + i] = ldf<T>((const T*)pp[9] + i);
    for (int i = t; i < 32;   i += 256) wsf[ON1W + i] = ldf<T>((const T*)pp[10] + i);
    for (int i = t; i < 32;   i += 256) wsf[ON1B + i] = ldf<T>((const T*)pp[11] + i);
    for (int i = t; i < 32;   i += 256) wsf[ON2W + i] = ldf<T>((const T*)pp[12] + i);
    for (int i = t; i < 32;   i += 256) wsf[ON2B + i] = ldf<T>((const T*)pp[13] + i);
    for (int i = t; i < 32;   i += 256) wsf[OBETA + i] = ldf<T>((const T*)pp[14] + i);
    for (int i = t; i < 32;   i += 256) wsf[OGAMMA + i] = ldf<T>((const T*)pp[15] + i);
    for (int i = t; i < 128;  i += 256) wsf[OSUMS + i] = 0.f;
}

__global__ __launch_bounds__(256) void k_setup(
    const unsigned short* __restrict__ raw, const void* __restrict__ cwsrc,
    const void* p2, const void* p3, const void* p4, const void* p5,
    const void* p6, const void* p7, const void* p8, const void* p9,
    const void* p10, const void* p11, const void* p12, const void* p13,
    const void* p14, const void* p15, const void* p16, const void* p17,
    float* __restrict__ wsf, float* __restrict__ cwt,
    unsigned* __restrict__ t1u, int* __restrict__ flagp)
{
    __shared__ int sbad;
    if (threadIdx.x == 0) sbad = 0;
    __syncthreads();
    int bad = 0;
    for (int k = 0; k < 8; ++k) {
        unsigned short u = raw[2 * (threadIdx.x * 8 + k)];
        float v = __uint_as_float(((unsigned)u) << 16);
        if (!(fabsf(v) < 1e6f)) bad = 1;
    }
    if (bad) sbad = 1;
    __syncthreads();
    int flag = sbad ? 0 : 1;

    int bid = blockIdx.x;
    if (bid == 0) {
        const void* pp[16] = {p2,p3,p4,p5,p6,p7,p8,p9,p10,p11,p12,p13,p14,p15,p16,p17};
        if (flag == 0) prep_body<float>(pp, wsf);
        else           prep_body<bf16>(pp, wsf);
        if (threadIdx.x == 0) *flagp = flag;
    }
    if (bid < 128) {   // zero padded borders of the 128 pair-planes
        unsigned* pl = t1u + (size_t)bid * PPU_;
        for (int i = threadIdx.x; i < 258; i += 256) { pl[i] = 0; pl[257*258 + i] = 0; }
        int r = threadIdx.x + 1;
        pl[r * 258] = 0; pl[r * 258 + 257] = 0;
    }
    // transpose cw -> cwt[b][g(1024)][j(576)], j = q*2+half, plane p = q + 288*half
    int base = bid * 2304;
    if (flag == 1) {
        const unsigned short* s = (const unsigned short*)cwsrc;
        for (int i = threadIdx.x; i < 2304; i += 256) {
            int o = base + i;
            int b = o / 589824; int r = o - b * 589824;
            int g = r / 576;    int j = r - g * 576;
            int p = (j >> 1) + 288 * (j & 1);
            cwt[o] = us2f(s[(size_t)(b * 576 + p) * 1024 + g]);
        }
    } else {
        const float* s = (const float*)cwsrc;
        for (int i = threadIdx.x; i < 2304; i += 256) {
            int o = base + i;
            int b = o / 589824; int r = o - b * 589824;
            int g = r / 576;    int j = r - g * 576;
            int p = (j >> 1) + 288 * (j & 1);
            cwt[o] = s[(size_t)(b * 576 + p) * 1024 + g];
        }
    }
}

// ---------------- k_ln1: LN + conv1, 2 px/thread, uniform weight reads ----------------
template<typename T>
__device__ void ln1_body(const T* __restrict__ inp, const float* __restrict__ wsf,
                         unsigned* __restrict__ t1u)
{
    int b = blockIdx.x >> 7;
    int po = ((blockIdx.x & 127) * 256 + threadIdx.x) * 2;
    int h = po >> 8, w = po & 255;

    float2 v[32];
    #pragma unroll
    for (int ch = 0; ch < 32; ++ch) {
        const T* ip = inp + (size_t)(b * 32 + ch) * P_ + po;
        v[ch] = make_float2(ldf<T>(ip), ldf<T>(ip + 1));
    }
    float m0 = 0.f, m1 = 0.f;
    #pragma unroll
    for (int ch = 0; ch < 32; ++ch) { m0 += v[ch].x; m1 += v[ch].y; }
    m0 *= (1.f/32); m1 *= (1.f/32);
    float s0 = 0.f, s1 = 0.f;
    #pragma unroll
    for (int ch = 0; ch < 32; ++ch) {
        float d0 = v[ch].x - m0, d1 = v[ch].y - m1;
        s0 += d0*d0; s1 += d1*d1;
    }
    float i0 = rsqrtf(s0*(1.f/32) + 1e-6f), i1 = rsqrtf(s1*(1.f/32) + 1e-6f);
    #pragma unroll
    for (int ch = 0; ch < 32; ++ch) {
        float g = wsf[ON1W + ch], bb = wsf[ON1B + ch];
        v[ch].x = (v[ch].x - m0)*i0*g + bb;
        v[ch].y = (v[ch].y - m1)*i1*g + bb;
    }

    unsigned* dstb = t1u + (size_t)(b * 32) * PPU_ + (h + 1) * PSTR_ + (w + 1);
    #pragma unroll 4
    for (int o = 0; o < 32; ++o) {
        float a0 = wsf[OB1 + o],      a1 = a0;
        float c0 = wsf[OB1 + 32 + o], c1 = c0;
        #pragma unroll
        for (int ch = 0; ch < 32; ++ch) {
            float wa = wsf[OW1 + o*32 + ch];
            float wb = wsf[OW1 + (o+32)*32 + ch];
            a0 += v[ch].x * wa; a1 += v[ch].y * wa;
            c0 += v[ch].x * wb; c1 += v[ch].y * wb;
        }
        unsigned* dst = dstb + (size_t)o * PPU_;
        dst[0] = pkf(a0, c0);
        dst[1] = pkf(a1, c1);
    }
}

__global__ __launch_bounds__(256) void k_ln1(const void* __restrict__ inp,
        const float* __restrict__ wsf, unsigned* __restrict__ t1u,
        const int* __restrict__ flag)
{
    if (*flag == 0) ln1_body<float>((const float*)inp, wsf, t1u);
    else            ln1_body<bf16>((const bf16*)inp, wsf, t1u);
}

// ---------------- k_ddf v5: 2048 blocks, LDS t1 tile + transposed filter staging ----------------
// block: b = bid>>9, half = (bid>>8)&1 (channels half*16..+16), tile tb = bid&255 (16x16 px)
__global__ __launch_bounds__(256) void k_ddf(const unsigned* __restrict__ t1u,
        const float* __restrict__ cwt, unsigned* __restrict__ g32,
        float* __restrict__ sums)
{
    __shared__ float V[5184];      // [qr=cpl*9+tap (144)][rr 4][cc 4][hf 2], stride 36
    __shared__ unsigned T[5184];   // [pi 16][row 18][col 18]

    int bid = blockIdx.x;
    int b = bid >> 9;
    int half = (bid >> 8) & 1;
    int tb = bid & 255;
    int tbr = tb >> 4, tbc = tb & 15;
    int cp0 = half * 16;
    int top = tbr * 16, left = tbc * 16;

    // --- V staging: 16 grid positions x 288 contiguous floats each ---
    {
        const float* cwtb = cwt + (size_t)b * (1024 * 576);
        for (int idx = threadIdx.x; idx < 4608; idx += 256) {
            int pos = idx / 288;
            int e = idx - pos * 288;
            int wr = pos >> 2, wc = pos & 3;
            int grow = tbr*2 - 1 + wr; grow = grow < 0 ? 0 : (grow > 31 ? 31 : grow);
            int gcol = tbc*2 - 1 + wc; gcol = gcol < 0 ? 0 : (gcol > 31 ? 31 : gcol);
            int g = grow * 32 + gcol;
            float val = cwtb[(size_t)g * 576 + cp0 * 18 + e];
            V[(e >> 1) * 36 + wr * 8 + wc * 2 + (e & 1)] = val;
        }
    }
    // --- T staging: 16 planes x 18 rows x 18 u32, coalesced uint2 runs ---
    {
        const unsigned* tb1 = t1u + (size_t)(b * 32 + cp0) * PPU_;
        for (int idx = threadIdx.x; idx < 2592; idx += 256) {
            int run = idx / 9;
            int cpair = idx - run * 9;
            int pi = run / 18;
            int row = run - pi * 18;
            uint2 u = *(const uint2*)(tb1 + (size_t)pi * PPU_ + (top + row) * PSTR_ + left + cpair * 2);
            *(uint2*)&T[pi * 324 + row * 18 + cpair * 2] = u;
        }
    }
    __syncthreads();

    int wid = threadIdx.x >> 6, lane = threadIdx.x & 63;
    int cell_r = lane >> 5, cell_c = (lane >> 4) & 1;
    int tr = (lane >> 2) & 3, tc = lane & 3;
    int lr0 = cell_r * 8 + 2 * tr;
    int lc0 = cell_c * 8 + 2 * tc;
    int h0 = top + lr0, w0 = left + lc0;
    int kt = cell_r + (tr >> 1), kl = cell_c + (tc >> 1);

    float fh0 = (2*tr)*0.125f + ((tr < 2) ? 0.5625f : -0.4375f);
    float fh1 = fh0 + 0.125f;
    float fw0 = (2*tc)*0.125f + ((tc < 2) ? 0.5625f : -0.4375f);
    float fw1 = fw0 + 0.125f;
    float aw[2][2][4];
    #pragma unroll
    for (int dr = 0; dr < 2; ++dr) {
        float fh = dr ? fh1 : fh0;
        #pragma unroll
        for (int dc = 0; dc < 2; ++dc) {
            float fw = dc ? fw1 : fw0;
            aw[dr][dc][0] = (1.f-fh)*(1.f-fw);
            aw[dr][dc][1] = (1.f-fh)*fw;
            aw[dr][dc][2] = fh*(1.f-fw);
            aw[dr][dc][3] = fh*fw;
        }
    }

    for (int cl = 0; cl < 4; ++cl) {
        int cpl = wid * 4 + cl;          // local channel 0..15
        int cp = cp0 + cpl;

        float P1[4][4], P2[4][4];
        const unsigned* tp = &T[cpl * 324 + lr0 * 18 + lc0];
        #pragma unroll
        for (int rr = 0; rr < 4; ++rr) {
            uint2 ua = *(const uint2*)(tp + rr * 18);
            uint2 ub = *(const uint2*)(tp + rr * 18 + 2);
            P1[rr][0] = lo16f(ua.x); P2[rr][0] = hi16f(ua.x);
            P1[rr][1] = lo16f(ua.y); P2[rr][1] = hi16f(ua.y);
            P1[rr][2] = lo16f(ub.x); P2[rr][2] = hi16f(ub.x);
            P1[rr][3] = lo16f(ub.y); P2[rr][3] = hi16f(ub.y);
        }

        float acc1[2][2] = {{0.f,0.f},{0.f,0.f}};
        float acc2[2][2] = {{0.f,0.f},{0.f,0.f}};
        const float* q1 = &V[(cpl * 9) * 36 + kt * 8 + kl * 2];
        #pragma unroll
        for (int i = 0; i < 3; ++i) {
            #pragma unroll
            for (int j = 0; j < 3; ++j) {
                int toff = (i * 3 + j) * 36;
                float2 c00 = *(const float2*)(q1 + toff);
                float2 c01 = *(const float2*)(q1 + toff + 2);
                float2 c10 = *(const float2*)(q1 + toff + 8);
                float2 c11 = *(const float2*)(q1 + toff + 10);
                #pragma unroll
                for (int dr = 0; dr < 2; ++dr) {
                    #pragma unroll
                    for (int dc = 0; dc < 2; ++dc) {
                        float f1 = aw[dr][dc][0]*c00.x + aw[dr][dc][1]*c01.x
                                 + aw[dr][dc][2]*c10.x + aw[dr][dc][3]*c11.x;
                        float f2 = aw[dr][dc][0]*c00.y + aw[dr][dc][1]*c01.y
                                 + aw[dr][dc][2]*c10.y + aw[dr][dc][3]*c11.y;
                        acc1[dr][dc] += P1[dr+i][dc+j] * f1;
                        acc2[dr][dc] += P2[dr+i][dc+j] * f2;
                    }
                }
            }
        }

        float g00 = acc1[0][0]*acc2[0][0], g01 = acc1[0][1]*acc2[0][1];
        float g10 = acc1[1][0]*acc2[1][0], g11 = acc1[1][1]*acc2[1][1];
        unsigned* gp = g32 + (size_t)(b * 32 + cp) * 32768 + h0 * 128 + (w0 >> 1);
        gp[0]   = pkf(g00, g01);
        gp[128] = pkf(g10, g11);

        float s = g00 + g01 + g10 + g11;
        #pragma unroll
        for (int off = 32; off >= 1; off >>= 1) s += __shfl_xor(s, off, 64);
        if (lane == 0) atomicAdd(&sums[b * 32 + cp], s);
    }
}

// ---------------- k_sca ----------------
__global__ void k_sca(float* __restrict__ wsf)
{
    int t = threadIdx.x;            // 128
    int b = t >> 5, o = t & 31;
    float acc = wsf[OBS + o];
    #pragma unroll
    for (int ch = 0; ch < C_; ++ch)
        acc += wsf[OWS + o*C_ + ch] * (wsf[OSUMS + b*C_ + ch] * (1.f/(float)P_));
    wsf[OSVEC + b*C_ + o] = acc;
}

// ---------------- k_tail: 1 px/thread, uniform (s_load) weight reads ----------------
template<typename T>
__device__ void tail_body(const T* __restrict__ inp, const unsigned short* __restrict__ gsh,
                          const float* __restrict__ wsf, T* __restrict__ out)
{
    int gt = blockIdx.x * 256 + threadIdx.x;
    int b = gt >> 16;
    int p = gt & 65535;
    const unsigned short* gp = gsh + (size_t)(b * 32) * P_ + p;
    const T* ip = inp + (size_t)(b * 32) * P_ + p;

    float x[32];
    #pragma unroll
    for (int ch = 0; ch < 32; ++ch)
        x[ch] = us2f(gp[(size_t)ch * P_]) * wsf[OSVEC + b*32 + ch];

    float y[32];
    #pragma unroll 4
    for (int o = 0; o < 32; ++o) {
        float acc = wsf[OB3 + o];
        #pragma unroll
        for (int ch = 0; ch < 32; ++ch) acc += x[ch] * wsf[OW3 + o*32 + ch];
        y[o] = ldf<T>(ip + (size_t)o * P_) + acc * wsf[OBETA + o];
    }

    float m = 0.f;
    #pragma unroll
    for (int ch = 0; ch < 32; ++ch) m += y[ch];
    m *= (1.f/32);
    float var = 0.f;
    #pragma unroll
    for (int ch = 0; ch < 32; ++ch) { float d = y[ch] - m; var += d*d; }
    float inv = rsqrtf(var*(1.f/32) + 1e-6f);
    float yn[32];
    #pragma unroll
    for (int ch = 0; ch < 32; ++ch)
        yn[ch] = (y[ch] - m)*inv * wsf[ON2W + ch] + wsf[ON2B + ch];

    float u[32];
    #pragma unroll 2
    for (int o = 0; o < 32; ++o) {
        float a = wsf[OB4 + o], bb = wsf[OB4 + 32 + o];
        #pragma unroll
        for (int ch = 0; ch < 32; ++ch) {
            a  += yn[ch] * wsf[OW4 + o*32 + ch];
            bb += yn[ch] * wsf[OW4 + (o+32)*32 + ch];
        }
        u[o] = a * bb;
    }

    T* op = out + (size_t)(b * 32) * P_ + p;
    #pragma unroll 4
    for (int o = 0; o < 32; ++o) {
        float acc = wsf[OB5 + o];
        #pragma unroll
        for (int ch = 0; ch < 32; ++ch) acc += u[ch] * wsf[OW5 + o*32 + ch];
        float res = y[o] + acc * wsf[OGAMMA + o];
        if constexpr (sizeof(T) == 4) op[(size_t)o * P_] = res;
        else op[(size_t)o * P_] = (T)__float2bfloat16(res);
    }
}

__global__ __launch_bounds__(256) void k_tail(const void* __restrict__ inp,
        const unsigned short* __restrict__ gsh, const float* __restrict__ wsf,
        void* __restrict__ out, const int* __restrict__ flag)
{
    if (*flag == 0) tail_body<float>((const float*)inp, gsh, wsf, (float*)out);
    else            tail_body<bf16>((const bf16*)inp, gsh, wsf, (bf16*)out);
}

extern "C" void kernel_launch(void* const* d_in, const int* in_sizes, int n_in,
                              void* d_out, int out_size, void* d_ws, size_t ws_size,
                              hipStream_t stream)
{
    float* wsf = (float*)d_ws;
    char* wsb = (char*)d_ws;
    float* cwt = (float*)(wsb + CWT_BOFF);
    unsigned* t1u = (unsigned*)(wsb + T1_BOFF);
    unsigned* g32 = (unsigned*)(wsb + G_BOFF);
    int* flag = (int*)(wsf + OFLAG);

    k_setup<<<1024, 256, 0, stream>>>(
        (const unsigned short*)d_in[0], d_in[1],
        d_in[2], d_in[3], d_in[4], d_in[5], d_in[6], d_in[7], d_in[8], d_in[9],
        d_in[10], d_in[11], d_in[12], d_in[13], d_in[14], d_in[15], d_in[16], d_in[17],
        wsf, cwt, t1u, flag);

    k_ln1<<<512, 256, 0, stream>>>(d_in[0], wsf, t1u, flag);

    k_ddf<<<2048, 256, 0, stream>>>(t1u, cwt, g32, wsf + OSUMS);

    k_sca<<<1, 128, 0, stream>>>(wsf);

    k_tail<<<1024, 256, 0, stream>>>(d_in[0], (const unsigned short*)g32, wsf,
                                     d_out, flag);
}

// Round 7
// 369.462 us; speedup vs baseline: 1.1497x; 1.1497x over previous
//
#include <hip/hip_runtime.h>
#include <hip/hip_bf16.h>

typedef __hip_bfloat16 bf16;

#define B_   4
#define C_   32
#define DW_  64
#define H_   256
#define W_   256
#define P_   65536
#define SRC_ 32
#define PPU_ 66564          // padded pair-plane, u32 elements (258*258)
#define PSTR_ 258

// ---- ws float-index offsets (small region) ----
#define OW1    0
#define OB1    2048
#define OW3    2112
#define OB3    3136
#define OWS    3168
#define OBS    4192
#define OW4    4224
#define OB4    6272
#define OW5    6336
#define OB5    7360
#define ON1W   7392
#define ON1B   7424
#define ON2W   7456
#define ON2B   7488
#define OBETA  7520
#define OGAMMA 7552
#define OSUMS  7584
#define OSVEC  7712
#define OFLAG  7900
// byte offsets
#define T1_BOFF  40960ull                        // paired padded t1: 128*66564*4 = 34080768 B
#define G_BOFF   (T1_BOFF + 34080768ull)         // g bf16 pair-packed: 16777216 B

__device__ __forceinline__ float lo16f(unsigned u){ return __uint_as_float(u << 16); }
__device__ __forceinline__ float hi16f(unsigned u){ return __uint_as_float(u & 0xFFFF0000u); }
__device__ __forceinline__ float us2f(unsigned short u){ return __uint_as_float(((unsigned)u) << 16); }
__device__ __forceinline__ unsigned short bbits(float v){
    union { bf16 b; unsigned short u; } cv; cv.b = __float2bfloat16(v); return cv.u;
}
__device__ __forceinline__ unsigned pkf(float lo, float hi){
    return ((unsigned)bbits(hi) << 16) | bbits(lo);
}

template<typename T> __device__ __forceinline__ float ldf(const T* p);
template<> __device__ __forceinline__ float ldf<float>(const float* p){ return *p; }
template<> __device__ __forceinline__ float ldf<bf16>(const bf16* p){ return __bfloat162float(*p); }

// ---------------- k_setup: flag + weight prep + zpad (128 blocks) ----------------
template<typename T>
__device__ void prep_body(const void* const* pp, float* wsf)
{
    int t = threadIdx.x;
    for (int i = t; i < 2048; i += 256) wsf[OW1 + i] = ldf<T>((const T*)pp[0] + i);
    for (int i = t; i < 64;   i += 256) wsf[OB1 + i] = ldf<T>((const T*)pp[1] + i);
    for (int i = t; i < 1024; i += 256) wsf[OW3 + i] = ldf<T>((const T*)pp[2] + i);
    for (int i = t; i < 32;   i += 256) wsf[OB3 + i] = ldf<T>((const T*)pp[3] + i);
    for (int i = t; i < 1024; i += 256) wsf[OWS + i] = ldf<T>((const T*)pp[4] + i);
    for (int i = t; i < 32;   i += 256) wsf[OBS + i] = ldf<T>((const T*)pp[5] + i);
    for (int i = t; i < 2048; i += 256) wsf[OW4 + i] = ldf<T>((const T*)pp[6] + i);
    for (int i = t; i < 64;   i += 256) wsf[OB4 + i] = ldf<T>((const T*)pp[7] + i);
    for (int i = t; i < 1024; i += 256) wsf[OW5 + i] = ldf<T>((const T*)pp[8] + i);
    for (int i = t; i < 32;   i += 256) wsf[OB5 + i] = ldf<T>((const T*)pp[9] + i);
    for (int i = t; i < 32;   i += 256) wsf[ON1W + i] = ldf<T>((const T*)pp[10] + i);
    for (int i = t; i < 32;   i += 256) wsf[ON1B + i] = ldf<T>((const T*)pp[11] + i);
    for (int i = t; i < 32;   i += 256) wsf[ON2W + i] = ldf<T>((const T*)pp[12] + i);
    for (int i = t; i < 32;   i += 256) wsf[ON2B + i] = ldf<T>((const T*)pp[13] + i);
    for (int i = t; i < 32;   i += 256) wsf[OBETA + i] = ldf<T>((const T*)pp[14] + i);
    for (int i = t; i < 32;   i += 256) wsf[OGAMMA + i] = ldf<T>((const T*)pp[15] + i);
    for (int i = t; i < 128;  i += 256) wsf[OSUMS + i] = 0.f;
}

__global__ __launch_bounds__(256) void k_setup(
    const unsigned short* __restrict__ raw,
    const void* p2, const void* p3, const void* p4, const void* p5,
    const void* p6, const void* p7, const void* p8, const void* p9,
    const void* p10, const void* p11, const void* p12, const void* p13,
    const void* p14, const void* p15, const void* p16, const void* p17,
    float* __restrict__ wsf, unsigned* __restrict__ t1u, int* __restrict__ flagp)
{
    int bid = blockIdx.x;
    if (bid == 0) {
        __shared__ int sbad;
        if (threadIdx.x == 0) sbad = 0;
        __syncthreads();
        int bad = 0;
        for (int k = 0; k < 8; ++k) {
            unsigned short u = raw[2 * (threadIdx.x * 8 + k)];
            float v = __uint_as_float(((unsigned)u) << 16);
            if (!(fabsf(v) < 1e6f)) bad = 1;
        }
        if (bad) sbad = 1;
        __syncthreads();
        int flag = sbad ? 0 : 1;
        const void* pp[16] = {p2,p3,p4,p5,p6,p7,p8,p9,p10,p11,p12,p13,p14,p15,p16,p17};
        if (flag == 0) prep_body<float>(pp, wsf);
        else           prep_body<bf16>(pp, wsf);
        if (threadIdx.x == 0) *flagp = flag;
    }
    // zero padded borders of pair-plane `bid`
    unsigned* pl = t1u + (size_t)bid * PPU_;
    for (int i = threadIdx.x; i < 258; i += 256) { pl[i] = 0; pl[257*258 + i] = 0; }
    int r = threadIdx.x + 1;
    pl[r * 258] = 0; pl[r * 258 + 257] = 0;
}

// ---------------- k_ln1: LN + conv1, 2 px/thread, uniform weight reads ----------------
template<typename T>
__device__ void ln1_body(const T* __restrict__ inp, const float* __restrict__ wsf,
                         unsigned* __restrict__ t1u)
{
    int b = blockIdx.x >> 7;
    int po = ((blockIdx.x & 127) * 256 + threadIdx.x) * 2;
    int h = po >> 8, w = po & 255;

    float2 v[32];
    #pragma unroll
    for (int ch = 0; ch < 32; ++ch) {
        const T* ip = inp + (size_t)(b * 32 + ch) * P_ + po;
        v[ch] = make_float2(ldf<T>(ip), ldf<T>(ip + 1));
    }
    float m0 = 0.f, m1 = 0.f;
    #pragma unroll
    for (int ch = 0; ch < 32; ++ch) { m0 += v[ch].x; m1 += v[ch].y; }
    m0 *= (1.f/32); m1 *= (1.f/32);
    float s0 = 0.f, s1 = 0.f;
    #pragma unroll
    for (int ch = 0; ch < 32; ++ch) {
        float d0 = v[ch].x - m0, d1 = v[ch].y - m1;
        s0 += d0*d0; s1 += d1*d1;
    }
    float i0 = rsqrtf(s0*(1.f/32) + 1e-6f), i1 = rsqrtf(s1*(1.f/32) + 1e-6f);
    #pragma unroll
    for (int ch = 0; ch < 32; ++ch) {
        float g = wsf[ON1W + ch], bb = wsf[ON1B + ch];
        v[ch].x = (v[ch].x - m0)*i0*g + bb;
        v[ch].y = (v[ch].y - m1)*i1*g + bb;
    }

    unsigned* dstb = t1u + (size_t)(b * 32) * PPU_ + (h + 1) * PSTR_ + (w + 1);
    #pragma unroll 4
    for (int o = 0; o < 32; ++o) {
        float a0 = wsf[OB1 + o],      a1 = a0;
        float c0 = wsf[OB1 + 32 + o], c1 = c0;
        #pragma unroll
        for (int ch = 0; ch < 32; ++ch) {
            float wa = wsf[OW1 + o*32 + ch];
            float wb = wsf[OW1 + (o+32)*32 + ch];
            a0 += v[ch].x * wa; a1 += v[ch].y * wa;
            c0 += v[ch].x * wb; c1 += v[ch].y * wb;
        }
        unsigned* dst = dstb + (size_t)o * PPU_;
        dst[0] = pkf(a0, c0);
        dst[1] = pkf(a1, c1);
    }
}

__global__ __launch_bounds__(256) void k_ln1(const void* __restrict__ inp,
        const float* __restrict__ wsf, unsigned* __restrict__ t1u,
        const int* __restrict__ flag)
{
    if (*flag == 0) ln1_body<float>((const float*)inp, wsf, t1u);
    else            ln1_body<bf16>((const bf16*)inp, wsf, t1u);
}

// ---------------- k_ddf v7: 4 px/thread (2x2), corner-conv + blend ----------------
// grid 1024 = [b 4][cpg 4][tile 64 of 32x32 px]; block 256 thr; LDS = filter nodes only.
__global__ __launch_bounds__(256) void k_ddf(const unsigned* __restrict__ t1u,
        const void* __restrict__ cwsrc, unsigned* __restrict__ g32,
        float* __restrict__ sums, const int* __restrict__ flag)
{
    __shared__ float VL[5184];    // [cpl 8][node 36][tap 9][half 2]  20.7 KB

    int bid = blockIdx.x;
    int b   = bid >> 8;
    int cpg = (bid >> 6) & 3;
    int tb  = bid & 63;
    int tbr = tb >> 3, tbc = tb & 7;
    int top = tbr * 32, left = tbc * 32;
    int i0g = tbr * 4, j0g = tbc * 4;       // tile's first cell (8-px cells)
    int cp0 = cpg * 8;

    // --- stage filter corner nodes: gather from source (dtype-branch) ---
    bool isf = (*flag == 0);
    #pragma unroll 2
    for (int idx = threadIdx.x; idx < 5184; idx += 256) {
        int cp = idx / 648;  int r = idx - cp * 648;
        int node = r / 18;   int e = r - node * 18;
        int nr = node / 6,   nc = node - nr * 6;
        int gr = i0g - 1 + nr; gr = gr < 0 ? 0 : (gr > 31 ? 31 : gr);
        int gc = j0g - 1 + nc; gc = gc < 0 ? 0 : (gc > 31 ? 31 : gc);
        int g = gr * 32 + gc;
        int tap = e >> 1, half = e & 1;
        int p = (cp0 + cp) * 9 + tap + 288 * half;
        size_t sidx = (((size_t)(b * 576 + p)) << 10) + g;
        VL[idx] = isf ? ((const float*)cwsrc)[sidx]
                      : us2f(((const unsigned short*)cwsrc)[sidx]);
    }
    __syncthreads();

    int ti = threadIdx.x >> 4, tj = threadIdx.x & 15;
    int r0 = 2 * ti, c0 = 2 * tj;           // 2x2 px block, quadrant-aligned
    int rl = r0 & 7, cl = c0 & 7;
    int ci = r0 >> 3, cj = c0 >> 3;
    int sr = (rl >= 4), sc = (cl >= 4);
    float fh0 = 0.0625f * (float)(rl < 4 ? 2*rl + 9 : 2*rl - 7);
    float fw0 = 0.0625f * (float)(cl < 4 ? 2*cl + 9 : 2*cl - 7);
    float fh1 = fh0 + 0.125f, fw1 = fw0 + 0.125f;
    int nA = (ci + sr) * 6 + (cj + sc);     // TL corner node
    const int nodeofs[4] = {0, 1, 6, 7};    // TL TR BL BR

    float awk[4][4];                         // [corner k][px dr*2+dc]
    #pragma unroll
    for (int k = 0; k < 4; ++k) {
        int kr = k >> 1, kc = k & 1;
        #pragma unroll
        for (int px = 0; px < 4; ++px) {
            int dr = px >> 1, dc = px & 1;
            float fh = dr ? fh1 : fh0;
            float fw = dc ? fw1 : fw0;
            float wh = kr ? fh : 1.f - fh;
            float ww = kc ? fw : 1.f - fw;
            awk[k][px] = wh * ww;
        }
    }

    float sacc[8];
    #pragma unroll
    for (int i = 0; i < 8; ++i) sacc[i] = 0.f;

    for (int cpl = 0; cpl < 8; ++cpl) {
        int cp = cp0 + cpl;
        const unsigned* tp = t1u + (size_t)(b * 32 + cp) * PPU_
                           + (top + r0) * PSTR_ + (left + c0);
        float P1[4][4], P2[4][4];
        #pragma unroll
        for (int rr = 0; rr < 4; ++rr) {
            uint2 ua = *(const uint2*)(tp + rr * PSTR_);
            uint2 ub = *(const uint2*)(tp + rr * PSTR_ + 2);
            P1[rr][0] = lo16f(ua.x); P2[rr][0] = hi16f(ua.x);
            P1[rr][1] = lo16f(ua.y); P2[rr][1] = hi16f(ua.y);
            P1[rr][2] = lo16f(ub.x); P2[rr][2] = hi16f(ub.x);
            P1[rr][3] = lo16f(ub.y); P2[rr][3] = hi16f(ub.y);
        }

        float out[2][2][2] = {};
        #pragma unroll
        for (int k = 0; k < 4; ++k) {
            const float* Fb = &VL[cpl * 648 + (nA + nodeofs[k]) * 18];
            float ck[2][2][2] = {};
            #pragma unroll
            for (int i = 0; i < 3; ++i) {
                #pragma unroll
                for (int j = 0; j < 3; ++j) {
                    float2 F = *(const float2*)(Fb + 2 * (i * 3 + j));
                    #pragma unroll
                    for (int dr = 0; dr < 2; ++dr) {
                        #pragma unroll
                        for (int dc = 0; dc < 2; ++dc) {
                            ck[dr][dc][0] += P1[dr + i][dc + j] * F.x;
                            ck[dr][dc][1] += P2[dr + i][dc + j] * F.y;
                        }
                    }
                }
            }
            #pragma unroll
            for (int dr = 0; dr < 2; ++dr) {
                #pragma unroll
                for (int dc = 0; dc < 2; ++dc) {
                    float a = awk[k][dr * 2 + dc];
                    out[dr][dc][0] += a * ck[dr][dc][0];
                    out[dr][dc][1] += a * ck[dr][dc][1];
                }
            }
        }

        float g00 = out[0][0][0] * out[0][0][1];
        float g01 = out[0][1][0] * out[0][1][1];
        float g10 = out[1][0][0] * out[1][0][1];
        float g11 = out[1][1][0] * out[1][1][1];
        int gh = top + r0, gw = left + c0;
        unsigned* gp = g32 + (size_t)(b * 32 + cp) * 32768 + gh * 128 + (gw >> 1);
        gp[0]   = pkf(g00, g01);
        gp[128] = pkf(g10, g11);
        sacc[cpl] += g00 + g01 + g10 + g11;
    }

    int lane = threadIdx.x & 63;
    #pragma unroll
    for (int cpl = 0; cpl < 8; ++cpl) {
        float s = sacc[cpl];
        #pragma unroll
        for (int off = 32; off >= 1; off >>= 1) s += __shfl_xor(s, off, 64);
        if (lane == 0) atomicAdd(&sums[b * 32 + cp0 + cpl], s);
    }
}

// ---------------- k_sca ----------------
__global__ void k_sca(float* __restrict__ wsf)
{
    int t = threadIdx.x;            // 128
    int b = t >> 5, o = t & 31;
    float acc = wsf[OBS + o];
    #pragma unroll
    for (int ch = 0; ch < C_; ++ch)
        acc += wsf[OWS + o*C_ + ch] * (wsf[OSUMS + b*C_ + ch] * (1.f/(float)P_));
    wsf[OSVEC + b*C_ + o] = acc;
}

// ---------------- k_tail: 1 px/thread, uniform (s_load) weight reads ----------------
template<typename T>
__device__ void tail_body(const T* __restrict__ inp, const unsigned short* __restrict__ gsh,
                          const float* __restrict__ wsf, T* __restrict__ out)
{
    int gt = blockIdx.x * 256 + threadIdx.x;
    int b = gt >> 16;
    int p = gt & 65535;
    const unsigned short* gp = gsh + (size_t)(b * 32) * P_ + p;
    const T* ip = inp + (size_t)(b * 32) * P_ + p;

    float x[32];
    #pragma unroll
    for (int ch = 0; ch < 32; ++ch)
        x[ch] = us2f(gp[(size_t)ch * P_]) * wsf[OSVEC + b*32 + ch];

    float y[32];
    #pragma unroll 4
    for (int o = 0; o < 32; ++o) {
        float acc = wsf[OB3 + o];
        #pragma unroll
        for (int ch = 0; ch < 32; ++ch) acc += x[ch] * wsf[OW3 + o*32 + ch];
        y[o] = ldf<T>(ip + (size_t)o * P_) + acc * wsf[OBETA + o];
    }

    float m = 0.f;
    #pragma unroll
    for (int ch = 0; ch < 32; ++ch) m += y[ch];
    m *= (1.f/32);
    float var = 0.f;
    #pragma unroll
    for (int ch = 0; ch < 32; ++ch) { float d = y[ch] - m; var += d*d; }
    float inv = rsqrtf(var*(1.f/32) + 1e-6f);
    float yn[32];
    #pragma unroll
    for (int ch = 0; ch < 32; ++ch)
        yn[ch] = (y[ch] - m)*inv * wsf[ON2W + ch] + wsf[ON2B + ch];

    float u[32];
    #pragma unroll 2
    for (int o = 0; o < 32; ++o) {
        float a = wsf[OB4 + o], bb = wsf[OB4 + 32 + o];
        #pragma unroll
        for (int ch = 0; ch < 32; ++ch) {
            a  += yn[ch] * wsf[OW4 + o*32 + ch];
            bb += yn[ch] * wsf[OW4 + (o+32)*32 + ch];
        }
        u[o] = a * bb;
    }

    T* op = out + (size_t)(b * 32) * P_ + p;
    #pragma unroll 4
    for (int o = 0; o < 32; ++o) {
        float acc = wsf[OB5 + o];
        #pragma unroll
        for (int ch = 0; ch < 32; ++ch) acc += u[ch] * wsf[OW5 + o*32 + ch];
        float res = y[o] + acc * wsf[OGAMMA + o];
        if constexpr (sizeof(T) == 4) op[(size_t)o * P_] = res;
        else op[(size_t)o * P_] = (T)__float2bfloat16(res);
    }
}

__global__ __launch_bounds__(256) void k_tail(const void* __restrict__ inp,
        const unsigned short* __restrict__ gsh, const float* __restrict__ wsf,
        void* __restrict__ out, const int* __restrict__ flag)
{
    if (*flag == 0) tail_body<float>((const float*)inp, gsh, wsf, (float*)out);
    else            tail_body<bf16>((const bf16*)inp, gsh, wsf, (bf16*)out);
}

extern "C" void kernel_launch(void* const* d_in, const int* in_sizes, int n_in,
                              void* d_out, int out_size, void* d_ws, size_t ws_size,
                              hipStream_t stream)
{
    float* wsf = (float*)d_ws;
    char* wsb = (char*)d_ws;
    unsigned* t1u = (unsigned*)(wsb + T1_BOFF);
    unsigned* g32 = (unsigned*)(wsb + G_BOFF);
    int* flag = (int*)(wsf + OFLAG);

    k_setup<<<128, 256, 0, stream>>>(
        (const unsigned short*)d_in[0],
        d_in[2], d_in[3], d_in[4], d_in[5], d_in[6], d_in[7], d_in[8], d_in[9],
        d_in[10], d_in[11], d_in[12], d_in[13], d_in[14], d_in[15], d_in[16], d_in[17],
        wsf, t1u, flag);

    k_ln1<<<512, 256, 0, stream>>>(d_in[0], wsf, t1u, flag);

    k_ddf<<<1024, 256, 0, stream>>>(t1u, d_in[1], g32, wsf + OSUMS, flag);

    k_sca<<<1, 128, 0, stream>>>(wsf);

    k_tail<<<1024, 256, 0, stream>>>(d_in[0], (const unsigned short*)g32, wsf,
                                     d_out, flag);
}